// Round 2
// baseline (1915.332 us; speedup 1.0000x reference)
//
#include <hip/hip_runtime.h>
#include <hip/hip_bf16.h>
#include <stdint.h>

// ---------------------------------------------------------------------------
// GnnCritic fused forward, MI355X (gfx950) — v2.
//
// q{1,2}[b] = sum_n relu(relu(inp[n,b] @ W1 + b1) @ W2 + b2) @ wr + br
// inp[n,b]  = [obs_body(10) | obs_obj_n(15) | segmax_n(edge_features)(128)]
//
// v2 changes vs v1 (latency-bound, weights thrashing L2):
//  - nontemporal loads for ef/obs (stream-once) so packed weights stay
//    L2-resident; nontemporal store for out.
//  - wave split 2x4 (rows x cols): halves per-wave A-LDS b128 traffic.
//  - depth-1 register double-buffering of weight and A fragments.
// ---------------------------------------------------------------------------

#define B_TOT 65536
#define MB 64

typedef __bf16 bf16x8 __attribute__((ext_vector_type(8)));
typedef float f32x4 __attribute__((ext_vector_type(4)));
typedef float f32x4v __attribute__((ext_vector_type(4)));
typedef unsigned short u16x8 __attribute__((ext_vector_type(8)));

// packed-weight offsets in d_ws, in ushort units (each frag = 64 lanes x 8 bf16)
#define OFF_W1H 0        // 80 frags  (K=160: kf 0..4, 16 cfg)
#define OFF_W1L 40960
#define OFF_W2H 81920    // 128 frags (K=256: kf 0..7)
#define OFF_W2L 147456
#define OFF_W3H 212992
#define OFF_W3L 253952
#define OFF_W4H 294912
#define OFF_W4L 360448   // end = 425984 ushorts = 832 KB

__device__ inline unsigned short f2bf(float f) {  // round-to-nearest-even
  unsigned int u = __float_as_uint(f);
  u += 0x7fffu + ((u >> 16) & 1u);
  return (unsigned short)(u >> 16);
}
__device__ inline float bf2f(unsigned short h) {
  return __uint_as_float(((unsigned int)h) << 16);
}
__device__ inline void split2(float v, unsigned short& h, unsigned short& l) {
  h = f2bf(v);
  l = f2bf(v - bf2f(h));
}

// ---------------------------------------------------------------------------
// Prep: pack W (Kreal x 256 row-major fp32) into B-fragment order, hi/lo bf16.
// Fragment (kf,cfg): lane L, elem j holds W[kf*32 + (L>>4)*8 + j][cfg*16 + (L&15)].
// ---------------------------------------------------------------------------
__global__ void prep_weights(const float* __restrict__ w1, const float* __restrict__ w2,
                             const float* __restrict__ w3, const float* __restrict__ w4,
                             unsigned short* __restrict__ ws) {
  int bid = blockIdx.x;
  int lane = threadIdx.x;
  const float* w; int f, Kreal; unsigned short *oh, *ol;
  if (bid < 80)       { w = w1; f = bid;       Kreal = 153; oh = ws + OFF_W1H; ol = ws + OFF_W1L; }
  else if (bid < 208) { w = w2; f = bid - 80;  Kreal = 256; oh = ws + OFF_W2H; ol = ws + OFF_W2L; }
  else if (bid < 288) { w = w3; f = bid - 208; Kreal = 153; oh = ws + OFF_W3H; ol = ws + OFF_W3L; }
  else                { w = w4; f = bid - 288; Kreal = 256; oh = ws + OFF_W4H; ol = ws + OFF_W4L; }
  int kf = f >> 4, cfg = f & 15;
  int c  = cfg * 16 + (lane & 15);
  int kb = kf * 32 + (lane >> 4) * 8;
  u16x8 H, L;
#pragma unroll
  for (int j = 0; j < 8; ++j) {
    int k = kb + j;
    float v = (k < Kreal) ? w[k * 256 + c] : 0.f;
    unsigned short h, l; split2(v, h, l);
    H[j] = h; L[j] = l;
  }
  size_t idx = ((size_t)f * 64 + lane) * 8;
  *(u16x8*)(oh + idx) = H;
  *(u16x8*)(ol + idx) = L;
}

// ---------------------------------------------------------------------------
// Fragment loaders (depth-1 double-buffered in the caller)
// ---------------------------------------------------------------------------
__device__ __forceinline__ void loadW(bf16x8 (&Wb)[8], const unsigned short* WH,
                                      const unsigned short* WL, int kf) {
#pragma unroll
  for (int cf = 0; cf < 4; ++cf) {
    Wb[cf * 2 + 0] = *(const bf16x8*)(WH + (size_t)kf * 8192 + cf * 512);
    Wb[cf * 2 + 1] = *(const bf16x8*)(WL + (size_t)kf * 8192 + cf * 512);
  }
}
template<int AS>
__device__ __forceinline__ void loadA(bf16x8 (&Ab)[4], const unsigned short* A0h,
                                      const unsigned short* A0l, int kf) {
  Ab[0] = *(const bf16x8*)(A0h + kf * 32);
  Ab[1] = *(const bf16x8*)(A0l + kf * 32);
  Ab[2] = *(const bf16x8*)(A0h + 16 * AS + kf * 32);
  Ab[3] = *(const bf16x8*)(A0l + 16 * AS + kf * 32);
}

// GEMM over one staged A-tile (64 x 32*KF hi/lo in LDS) vs packed W.
// Wave (wr,wc) owns rows wr*32..+32, cols wc*64..+64.
// acc[rf][cf]: D rows wr*32+rf*16+(lane>>4)*4+i, col wc*64+cf*16+(lane&15).
template<int KF, int AS>
__device__ __forceinline__ void gemm2(const unsigned short* __restrict__ Ah,
                                      const unsigned short* __restrict__ Al,
                                      const unsigned short* __restrict__ wHb,
                                      const unsigned short* __restrict__ wLb,
                                      int lane, int wr, int wc, f32x4 acc[2][4]) {
  const int r0 = wr * 32 + (lane & 15);
  const int kg = (lane >> 4) * 8;
  const unsigned short* A0h = Ah + r0 * AS + kg;
  const unsigned short* A0l = Al + r0 * AS + kg;
  const size_t wof = ((size_t)(wc * 4) * 64 + lane) * 8;
  const unsigned short* WH = wHb + wof;
  const unsigned short* WL = wLb + wof;

  bf16x8 W[2][8], A[2][4];
  loadW(W[0], WH, WL, 0);
  loadA<AS>(A[0], A0h, A0l, 0);
#pragma unroll
  for (int kf = 0; kf < KF; ++kf) {
    const int cu = kf & 1, nx = cu ^ 1;
    if (kf + 1 < KF) {
      loadW(W[nx], WH, WL, kf + 1);
      loadA<AS>(A[nx], A0h, A0l, kf + 1);
    }
#pragma unroll
    for (int cf = 0; cf < 4; ++cf) {
#pragma unroll
      for (int rf = 0; rf < 2; ++rf) {
        acc[rf][cf] = __builtin_amdgcn_mfma_f32_16x16x32_bf16(A[cu][rf*2+0], W[cu][cf*2+0], acc[rf][cf], 0, 0, 0);
        acc[rf][cf] = __builtin_amdgcn_mfma_f32_16x16x32_bf16(A[cu][rf*2+1], W[cu][cf*2+0], acc[rf][cf], 0, 0, 0);
        acc[rf][cf] = __builtin_amdgcn_mfma_f32_16x16x32_bf16(A[cu][rf*2+0], W[cu][cf*2+1], acc[rf][cf], 0, 0, 0);
      }
    }
  }
}

__device__ __forceinline__ void zero_acc(f32x4 acc[2][4]) {
#pragma unroll
  for (int rf = 0; rf < 2; ++rf)
#pragma unroll
    for (int cf = 0; cf < 4; ++cf)
      acc[rf][cf] = (f32x4){0.f, 0.f, 0.f, 0.f};
}

__device__ __forceinline__ void store_hidden2(f32x4 acc[2][4], const float* bias,
                                              int lane, int wr, int wc,
                                              unsigned short (*Hh)[264], unsigned short (*Hl)[264]) {
  const int row0 = wr * 32 + ((lane >> 4) << 2);
  const int col0 = wc * 64 + (lane & 15);
#pragma unroll
  for (int rf = 0; rf < 2; ++rf)
#pragma unroll
    for (int cf = 0; cf < 4; ++cf) {
      int col = col0 + cf * 16;
      float bv = bias[col];
#pragma unroll
      for (int i = 0; i < 4; ++i) {
        int row = row0 + rf * 16 + i;
        float h = fmaxf(acc[rf][cf][i] + bv, 0.f);
        unsigned short hh, hl; split2(h, hh, hl);
        Hh[row][col] = hh; Hl[row][col] = hl;
      }
    }
}

__device__ __forceinline__ void accum_q2(f32x4 acc[2][4], const float* bias, const float* wrv,
                                         int lane, int wr, int wc, float qp[2][4]) {
  const int col0 = wc * 64 + (lane & 15);
#pragma unroll
  for (int rf = 0; rf < 2; ++rf)
#pragma unroll
    for (int cf = 0; cf < 4; ++cf) {
      int col = col0 + cf * 16;
      float bv = bias[col];
      float wv = wrv[col];
#pragma unroll
      for (int i = 0; i < 4; ++i) {
        float x = fmaxf(acc[rf][cf][i] + bv, 0.f);
        qp[rf][i] += x * wv;
      }
    }
}

// ---------------------------------------------------------------------------
// Main kernel: 512 threads (8 waves = 2 row-groups x 4 col-groups),
// 64 batch rows per block, grid = 1024. LDS ~116 KB -> 1 block/CU.
// ---------------------------------------------------------------------------
__global__ __launch_bounds__(512, 2) void gnn_fused(
    const float* __restrict__ obs, const float* __restrict__ ef, const int* __restrict__ eto,
    const unsigned short* __restrict__ ws,
    const float* __restrict__ b1, const float* __restrict__ b2,
    const float* __restrict__ b3, const float* __restrict__ b4,
    const float* __restrict__ wr1, const float* __restrict__ br1,
    const float* __restrict__ wr2, const float* __restrict__ br2,
    float* __restrict__ out) {
  // strides 168/264: 16B-aligned rows for ds_read_b128; read conflicts 2-way (free)
  __shared__ unsigned short A1h[64][168];
  __shared__ unsigned short A1l[64][168];
  __shared__ unsigned short A2h[64][264];
  __shared__ unsigned short A2l[64][264];
  __shared__ float sbias[4][256];
  __shared__ float swr[2][256];
  __shared__ float qbuf[2][2][4][32];   // [net][wr][wc][row32]

  const int tid  = threadIdx.x;
  const int lane = tid & 63;
  const int wave = tid >> 6;
  const int wr   = wave >> 2;
  const int wc   = wave & 3;
  const int b0   = blockIdx.x * MB;

  if (tid < 256) {
    sbias[0][tid] = b1[tid]; sbias[1][tid] = b2[tid];
    sbias[2][tid] = b3[tid]; sbias[3][tid] = b4[tid];
    swr[0][tid]   = wr1[tid]; swr[1][tid]  = wr2[tid];
  }
  int e2s[6];
#pragma unroll
  for (int e = 0; e < 6; ++e) e2s[e] = eto[e];

  float qp1[2][4] = {};
  float qp2[2][4] = {};

  for (int n = 0; n < 3; ++n) {
    // ---- build A1 = [body | obj_n | segmax_n(ef)] as hi/lo bf16 ----------
    // nontemporal: ef/obs are stream-once; keep packed weights L2-resident.
    for (int idx = tid; idx < 64 * 32; idx += 512) {   // cols 0..24
      int r = idx >> 5, k = idx & 31;
      if (k < 25) {
        int b = b0 + r;
        float v = (k < 10) ? __builtin_nontemporal_load(obs + b * 55 + k)
                           : __builtin_nontemporal_load(obs + b * 55 + 10 + n * 15 + (k - 10));
        unsigned short h, l; split2(v, h, l);
        A1h[r][k] = h; A1l[r][k] = l;
      }
    }
    for (int idx = tid; idx < 64 * 16; idx += 512) {   // zero pad 153..167
      int r = idx >> 4, k = 153 + (idx & 15);
      if (k < 168) { A1h[r][k] = 0; A1l[r][k] = 0; }
    }
#pragma unroll
    for (int it = 0; it < 4; ++it) {                   // segmax, cols 25..152
      int job = tid + it * 512;                        // 64 rows x 32 float4
      int r = job >> 5, dq = job & 31;
      size_t b = (size_t)(b0 + r);
      float m0 = -3.0e38f, m1 = m0, m2 = m0, m3 = m0;
#pragma unroll
      for (int e = 0; e < 6; ++e) {
        if (e2s[e] == n) {
          const f32x4v v = __builtin_nontemporal_load((const f32x4v*)(ef + (b * 6 + e) * 128 + dq * 4));
          m0 = fmaxf(m0, v[0]); m1 = fmaxf(m1, v[1]);
          m2 = fmaxf(m2, v[2]); m3 = fmaxf(m3, v[3]);
        }
      }
      int c = 25 + dq * 4;
      unsigned short h, l;
      split2(m0, h, l); A1h[r][c + 0] = h; A1l[r][c + 0] = l;
      split2(m1, h, l); A1h[r][c + 1] = h; A1l[r][c + 1] = l;
      split2(m2, h, l); A1h[r][c + 2] = h; A1l[r][c + 2] = l;
      split2(m3, h, l); A1h[r][c + 3] = h; A1l[r][c + 3] = l;
    }
    __syncthreads();

    { // net1 layer1 -> hidden
      f32x4 acc[2][4]; zero_acc(acc);
      gemm2<5, 168>(&A1h[0][0], &A1l[0][0], ws + OFF_W1H, ws + OFF_W1L, lane, wr, wc, acc);
      store_hidden2(acc, sbias[0], lane, wr, wc, A2h, A2l);
    }
    __syncthreads();
    { // net1 layer2 -> q1 partials
      f32x4 acc[2][4]; zero_acc(acc);
      gemm2<8, 264>(&A2h[0][0], &A2l[0][0], ws + OFF_W2H, ws + OFF_W2L, lane, wr, wc, acc);
      accum_q2(acc, sbias[1], swr[0], lane, wr, wc, qp1);
    }
    __syncthreads();
    { // net2 layer1
      f32x4 acc[2][4]; zero_acc(acc);
      gemm2<5, 168>(&A1h[0][0], &A1l[0][0], ws + OFF_W3H, ws + OFF_W3L, lane, wr, wc, acc);
      store_hidden2(acc, sbias[2], lane, wr, wc, A2h, A2l);
    }
    __syncthreads();
    { // net2 layer2 -> q2 partials
      f32x4 acc[2][4]; zero_acc(acc);
      gemm2<8, 264>(&A2h[0][0], &A2l[0][0], ws + OFF_W4H, ws + OFF_W4L, lane, wr, wc, acc);
      accum_q2(acc, sbias[3], swr[1], lane, wr, wc, qp2);
    }
  }

  // ---- readout reduce: sum q-partials over the 16 col-lanes, then waves ----
#pragma unroll
  for (int rf = 0; rf < 2; ++rf)
#pragma unroll
    for (int i = 0; i < 4; ++i) {
      float v1 = qp1[rf][i], v2 = qp2[rf][i];
#pragma unroll
      for (int m = 1; m < 16; m <<= 1) {
        v1 += __shfl_xor(v1, m);
        v2 += __shfl_xor(v2, m);
      }
      if ((lane & 15) == 0) {
        int row32 = rf * 16 + ((lane >> 4) << 2) + i;
        qbuf[0][wr][wc][row32] = v1;
        qbuf[1][wr][wc][row32] = v2;
      }
    }
  __syncthreads();
  if (tid < 128) {
    int net = tid >> 6, r = tid & 63;
    float s = 0.f;
#pragma unroll
    for (int w = 0; w < 4; ++w) s += qbuf[net][r >> 5][w][r & 31];
    s += net ? br2[0] : br1[0];
    __builtin_nontemporal_store(s, out + net * B_TOT + b0 + r);
  }
}

// ---------------------------------------------------------------------------
extern "C" void kernel_launch(void* const* d_in, const int* in_sizes, int n_in,
                              void* d_out, int out_size, void* d_ws, size_t ws_size,
                              hipStream_t stream) {
  (void)in_sizes; (void)n_in; (void)out_size; (void)ws_size;
  const float* obs = (const float*)d_in[0];
  // d_in[1] (act) is unused by the reference.
  const float* ef  = (const float*)d_in[2];
  const int*   eto = (const int*)d_in[3];
  const float* w1  = (const float*)d_in[4];  const float* b1  = (const float*)d_in[5];
  const float* w2  = (const float*)d_in[6];  const float* b2  = (const float*)d_in[7];
  const float* w3  = (const float*)d_in[8];  const float* b3  = (const float*)d_in[9];
  const float* w4  = (const float*)d_in[10]; const float* b4  = (const float*)d_in[11];
  const float* wr1 = (const float*)d_in[12]; const float* br1 = (const float*)d_in[13];
  const float* wr2 = (const float*)d_in[14]; const float* br2 = (const float*)d_in[15];
  float* out = (float*)d_out;
  unsigned short* ws = (unsigned short*)d_ws;  // needs 832 KB

  prep_weights<<<416, 64, 0, stream>>>(w1, w2, w3, w4, ws);
  gnn_fused<<<B_TOT / MB, 512, 0, stream>>>(obs, ef, eto, ws,
                                            b1, b2, b3, b4, wr1, br1, wr2, br2, out);
}

// Round 5
// 853.306 us; speedup vs baseline: 2.2446x; 2.2446x over previous
//
#include <hip/hip_runtime.h>
#include <hip/hip_bf16.h>
#include <stdint.h>

// ---------------------------------------------------------------------------
// GnnCritic fused forward, MI355X (gfx950) — v3 (resubmit x2; round-3 and
// round-4 benches never ran: GPU acquisition timeouts).
//
// q{1,2}[b] = sum_n relu(relu(inp[n,b] @ W1 + b1) @ W2 + b2) @ wr + br
// inp[n,b]  = [obs_body(10) | obs_obj_n(15) | segmax_n(edge_features)(128)]
//
// v3 vs v2 (both v1/v2 were scratch-bound: WRITE_SIZE 0.83/1.46 GB vs 0.5 MB
// of real stores = private-memory spill traffic):
//  - ALL GEMM phases macro-expanded in the kernel body; accumulators and
//    fragments are NAMED f32x4/bf16x8 variables (no arrays, no by-pointer
//    aggregates, nothing for SROA to miss). Target: localMem = 0.
//  - reverted v2's register double-buffer and 2x4 wave split (2x4 doubles
//    per-CU L2 weight traffic: 1170 vs 585 cyc/kf; 1x8 is balanced).
//  - kept nt loads on ef (stream-once) so packed weights stay L2-resident.
// ---------------------------------------------------------------------------

#define B_TOT 65536
#define MB 64

typedef __bf16 bf16x8 __attribute__((ext_vector_type(8)));
typedef float f32x4 __attribute__((ext_vector_type(4)));
typedef unsigned short u16x8 __attribute__((ext_vector_type(8)));

// packed-weight offsets in d_ws, in ushort units (frag = 64 lanes x 8 bf16)
#define OFF_W1H 0        // 80 frags  (K=160: kf 0..4, 16 cfg)
#define OFF_W1L 40960
#define OFF_W2H 81920    // 128 frags (K=256: kf 0..7)
#define OFF_W2L 147456
#define OFF_W3H 212992
#define OFF_W3L 253952
#define OFF_W4H 294912
#define OFF_W4L 360448   // end = 425984 ushorts = 832 KB

__device__ __forceinline__ unsigned short f2bf(float f) {  // RNE
  unsigned int u = __float_as_uint(f);
  u += 0x7fffu + ((u >> 16) & 1u);
  return (unsigned short)(u >> 16);
}
__device__ __forceinline__ float bf2f(unsigned short h) {
  return __uint_as_float(((unsigned int)h) << 16);
}
__device__ __forceinline__ void split2(float v, unsigned short& h, unsigned short& l) {
  h = f2bf(v);
  l = f2bf(v - bf2f(h));
}

// ---------------------------------------------------------------------------
// Prep: pack W (Kreal x 256 row-major fp32) into B-fragment order, hi/lo bf16.
// Fragment (kf,cfg): lane L, elem j holds W[kf*32 + (L>>4)*8 + j][cfg*16 + (L&15)].
// ---------------------------------------------------------------------------
__global__ void prep_weights(const float* __restrict__ w1, const float* __restrict__ w2,
                             const float* __restrict__ w3, const float* __restrict__ w4,
                             unsigned short* __restrict__ ws) {
  int bid = blockIdx.x;
  int lane = threadIdx.x;
  const float* w; int f, Kreal; unsigned short *oh, *ol;
  if (bid < 80)       { w = w1; f = bid;       Kreal = 153; oh = ws + OFF_W1H; ol = ws + OFF_W1L; }
  else if (bid < 208) { w = w2; f = bid - 80;  Kreal = 256; oh = ws + OFF_W2H; ol = ws + OFF_W2L; }
  else if (bid < 288) { w = w3; f = bid - 208; Kreal = 153; oh = ws + OFF_W3H; ol = ws + OFF_W3L; }
  else                { w = w4; f = bid - 288; Kreal = 256; oh = ws + OFF_W4H; ol = ws + OFF_W4L; }
  int kf = f >> 4, cfg = f & 15;
  int c  = cfg * 16 + (lane & 15);
  int kb = kf * 32 + (lane >> 4) * 8;
  u16x8 H, L;
#pragma unroll
  for (int j = 0; j < 8; ++j) {
    int k = kb + j;
    float v = (k < Kreal) ? w[k * 256 + c] : 0.f;
    unsigned short h, l; split2(v, h, l);
    H[j] = h; L[j] = l;
  }
  size_t idx = ((size_t)f * 64 + lane) * 8;
  *(u16x8*)(oh + idx) = H;
  *(u16x8*)(ol + idx) = L;
}

// ---------------------------------------------------------------------------
// GEMM-phase macros. All state is NAMED locals; everything static after the
// (fully unrolled) kf loop. Wave owns output cols wave*32..+32 (cfg wave*2+cf).
// acc cRF_CF: D rows rf*16 + (lane>>4)*4 + i, col = wave*32 + cf*16 + (lane&15).
// ---------------------------------------------------------------------------
#define Z4 ((f32x4){0.f, 0.f, 0.f, 0.f})

#define DECL_ACC \
  f32x4 c00 = Z4, c01 = Z4, c10 = Z4, c11 = Z4, c20 = Z4, c21 = Z4, c30 = Z4, c31 = Z4

#define MFMA3(CC, AH, AL, BH, BL)                                              \
  do {                                                                         \
    CC = __builtin_amdgcn_mfma_f32_16x16x32_bf16(AH, BH, CC, 0, 0, 0);         \
    CC = __builtin_amdgcn_mfma_f32_16x16x32_bf16(AL, BH, CC, 0, 0, 0);         \
    CC = __builtin_amdgcn_mfma_f32_16x16x32_bf16(AH, BL, CC, 0, 0, 0);         \
  } while (0)

// KF: #kf-rounds; AS: A-tile row stride (ushorts). AHB/ALB: per-thread A base
// (row lane&15, +((lane>>4)*8)). WHB/WLB: per-thread W base (+wave*1024+lane*8).
#define GEMM_KLOOP(KF, AS, AHB, ALB, WHB, WLB)                                 \
  _Pragma("unroll")                                                            \
  for (int kf = 0; kf < (KF); ++kf) {                                          \
    const unsigned short* ah_ = (AHB) + kf * 32;                               \
    const unsigned short* al_ = (ALB) + kf * 32;                               \
    bf16x8 a0h = *(const bf16x8*)(ah_ + 0 * 16 * (AS));                        \
    bf16x8 a1h = *(const bf16x8*)(ah_ + 1 * 16 * (AS));                        \
    bf16x8 a2h = *(const bf16x8*)(ah_ + 2 * 16 * (AS));                        \
    bf16x8 a3h = *(const bf16x8*)(ah_ + 3 * 16 * (AS));                        \
    bf16x8 a0l = *(const bf16x8*)(al_ + 0 * 16 * (AS));                        \
    bf16x8 a1l = *(const bf16x8*)(al_ + 1 * 16 * (AS));                        \
    bf16x8 a2l = *(const bf16x8*)(al_ + 2 * 16 * (AS));                        \
    bf16x8 a3l = *(const bf16x8*)(al_ + 3 * 16 * (AS));                        \
    const unsigned short* wh_ = (WHB) + (size_t)kf * 8192;                     \
    const unsigned short* wl_ = (WLB) + (size_t)kf * 8192;                     \
    bf16x8 b0h = *(const bf16x8*)(wh_);                                        \
    bf16x8 b0l = *(const bf16x8*)(wl_);                                        \
    bf16x8 b1h = *(const bf16x8*)(wh_ + 512);                                  \
    bf16x8 b1l = *(const bf16x8*)(wl_ + 512);                                  \
    MFMA3(c00, a0h, a0l, b0h, b0l);                                            \
    MFMA3(c10, a1h, a1l, b0h, b0l);                                            \
    MFMA3(c20, a2h, a2l, b0h, b0l);                                            \
    MFMA3(c30, a3h, a3l, b0h, b0l);                                            \
    MFMA3(c01, a0h, a0l, b1h, b1l);                                            \
    MFMA3(c11, a1h, a1l, b1h, b1l);                                            \
    MFMA3(c21, a2h, a2l, b1h, b1l);                                            \
    MFMA3(c31, a3h, a3l, b1h, b1l);                                            \
  }

// relu(acc+bias) -> split hi/lo -> A2 LDS tile (ushort scatter).
#define STORE_H_ONE(CC, RF, CF, BIASROW)                                       \
  do {                                                                         \
    int col = col0_ + (CF) * 16;                                               \
    float bv = (BIASROW)[col];                                                 \
    _Pragma("unroll")                                                          \
    for (int i = 0; i < 4; ++i) {                                              \
      int row = (RF) * 16 + row0_ + i;                                         \
      float h = fmaxf(CC[i] + bv, 0.f);                                        \
      unsigned short hh, hl; split2(h, hh, hl);                                \
      A2h[row][col] = hh; A2l[row][col] = hl;                                  \
    }                                                                          \
  } while (0)

#define STORE_H_ALL(BIASROW)                                                   \
  do {                                                                         \
    STORE_H_ONE(c00, 0, 0, BIASROW); STORE_H_ONE(c01, 0, 1, BIASROW);          \
    STORE_H_ONE(c10, 1, 0, BIASROW); STORE_H_ONE(c11, 1, 1, BIASROW);          \
    STORE_H_ONE(c20, 2, 0, BIASROW); STORE_H_ONE(c21, 2, 1, BIASROW);          \
    STORE_H_ONE(c30, 3, 0, BIASROW); STORE_H_ONE(c31, 3, 1, BIASROW);          \
  } while (0)

// relu(acc+bias)*wr accumulated into per-row q partial vector QPV (f32x4).
#define ACCQ_ONE(CC, CF, BIASROW, WRROW, QPV)                                  \
  do {                                                                         \
    int col = col0_ + (CF) * 16;                                               \
    float bv = (BIASROW)[col];                                                 \
    float wv = (WRROW)[col];                                                   \
    _Pragma("unroll")                                                          \
    for (int i = 0; i < 4; ++i) {                                              \
      float x = fmaxf(CC[i] + bv, 0.f);                                        \
      QPV[i] += x * wv;                                                        \
    }                                                                          \
  } while (0)

#define ACCQ_ALL(BIASROW, WRROW, Q0, Q1, Q2, Q3)                               \
  do {                                                                         \
    ACCQ_ONE(c00, 0, BIASROW, WRROW, Q0); ACCQ_ONE(c01, 1, BIASROW, WRROW, Q0);\
    ACCQ_ONE(c10, 0, BIASROW, WRROW, Q1); ACCQ_ONE(c11, 1, BIASROW, WRROW, Q1);\
    ACCQ_ONE(c20, 0, BIASROW, WRROW, Q2); ACCQ_ONE(c21, 1, BIASROW, WRROW, Q2);\
    ACCQ_ONE(c30, 0, BIASROW, WRROW, Q3); ACCQ_ONE(c31, 1, BIASROW, WRROW, Q3);\
  } while (0)

#define QREDUCE(QPV1, QPV2, RF)                                                \
  _Pragma("unroll")                                                            \
  for (int i = 0; i < 4; ++i) {                                                \
    float v1 = QPV1[i], v2 = QPV2[i];                                          \
    _Pragma("unroll")                                                          \
    for (int m = 1; m < 16; m <<= 1) {                                         \
      v1 += __shfl_xor(v1, m);                                                 \
      v2 += __shfl_xor(v2, m);                                                 \
    }                                                                          \
    if ((lane & 15) == 0) {                                                    \
      int row = (RF) * 16 + row0_ + i;                                         \
      qbuf[0][wave][row] = v1;                                                 \
      qbuf[1][wave][row] = v2;                                                 \
    }                                                                          \
  }

// ---------------------------------------------------------------------------
// Main kernel: 512 threads (8 waves, 1x8 row x col split), 64 batch rows per
// block, grid = 1024. LDS ~116 KB -> 1 block/CU (8 waves = 2/SIMD).
// ---------------------------------------------------------------------------
__global__ __launch_bounds__(512, 2) void gnn_fused(
    const float* __restrict__ obs, const float* __restrict__ ef, const int* __restrict__ eto,
    const unsigned short* __restrict__ ws,
    const float* __restrict__ b1, const float* __restrict__ b2,
    const float* __restrict__ b3, const float* __restrict__ b4,
    const float* __restrict__ wr1, const float* __restrict__ br1,
    const float* __restrict__ wr2, const float* __restrict__ br2,
    float* __restrict__ out) {
  // row strides 168/264 ushorts: 16B-aligned rows (ds_read_b128), stride mod
  // 32 dwords has gcd 4 -> 2-way read aliasing (free per m136).
  __shared__ __attribute__((aligned(16))) unsigned short A1h[64][168];
  __shared__ __attribute__((aligned(16))) unsigned short A1l[64][168];
  __shared__ __attribute__((aligned(16))) unsigned short A2h[64][264];
  __shared__ __attribute__((aligned(16))) unsigned short A2l[64][264];
  __shared__ float sbias[4][256];
  __shared__ float swr[2][256];
  __shared__ float qbuf[2][8][64];

  const int tid  = threadIdx.x;
  const int lane = tid & 63;
  const int wave = tid >> 6;
  const int b0   = blockIdx.x * MB;

  const int arow_ = lane & 15;          // A-frag row within 16-row group
  const int kg_   = (lane >> 4) * 8;    // k-slice within frag
  const int row0_ = (lane >> 4) << 2;   // C-frag row base
  const int col0_ = wave * 32 + arow_;  // C-frag col base
  const size_t wbase_ = (size_t)wave * 1024 + (size_t)lane * 8;

  if (tid < 256) {
    sbias[0][tid] = b1[tid]; sbias[1][tid] = b2[tid];
    sbias[2][tid] = b3[tid]; sbias[3][tid] = b4[tid];
    swr[0][tid]   = wr1[tid]; swr[1][tid]  = wr2[tid];
  }
  const int e0 = eto[0], e1 = eto[1], e2 = eto[2];
  const int e3 = eto[3], e4 = eto[4], e5 = eto[5];

  f32x4 qp1_0 = Z4, qp1_1 = Z4, qp1_2 = Z4, qp1_3 = Z4;
  f32x4 qp2_0 = Z4, qp2_1 = Z4, qp2_2 = Z4, qp2_3 = Z4;

  for (int n = 0; n < 3; ++n) {
    // ---- build A1 = [body | obj_n | segmax_n(ef)] as hi/lo bf16 ----------
    for (int idx = tid; idx < 64 * 32; idx += 512) {   // cols 0..24
      int r = idx >> 5, k = idx & 31;
      if (k < 25) {
        int b = b0 + r;
        float v = (k < 10) ? obs[b * 55 + k] : obs[b * 55 + 10 + n * 15 + (k - 10)];
        unsigned short h, l; split2(v, h, l);
        A1h[r][k] = h; A1l[r][k] = l;
      }
    }
    for (int idx = tid; idx < 64 * 16; idx += 512) {   // zero pad 153..167
      int r = idx >> 4, k = 153 + (idx & 15);
      if (k < 168) { A1h[r][k] = 0; A1l[r][k] = 0; }
    }
#pragma unroll
    for (int it = 0; it < 4; ++it) {                   // segmax, cols 25..152
      int job = tid + it * 512;                        // 64 rows x 32 float4
      int r = job >> 5, dq = job & 31;
      const float* efb = ef + ((size_t)(b0 + r) * 6) * 128 + dq * 4;
      float m0 = -3.0e38f, m1 = m0, m2 = m0, m3 = m0;
      // nt loads: ef is stream-once; keep packed weights L2-resident.
#define SEGMAX_EDGE(E, TGT)                                                    \
      if ((TGT) == n) {                                                        \
        f32x4 v = __builtin_nontemporal_load((const f32x4*)(efb + (E) * 128)); \
        m0 = fmaxf(m0, v[0]); m1 = fmaxf(m1, v[1]);                            \
        m2 = fmaxf(m2, v[2]); m3 = fmaxf(m3, v[3]);                            \
      }
      SEGMAX_EDGE(0, e0) SEGMAX_EDGE(1, e1) SEGMAX_EDGE(2, e2)
      SEGMAX_EDGE(3, e3) SEGMAX_EDGE(4, e4) SEGMAX_EDGE(5, e5)
#undef SEGMAX_EDGE
      int c = 25 + dq * 4;
      unsigned short h, l;
      split2(m0, h, l); A1h[r][c + 0] = h; A1l[r][c + 0] = l;
      split2(m1, h, l); A1h[r][c + 1] = h; A1l[r][c + 1] = l;
      split2(m2, h, l); A1h[r][c + 2] = h; A1l[r][c + 2] = l;
      split2(m3, h, l); A1h[r][c + 3] = h; A1l[r][c + 3] = l;
    }
    __syncthreads();

    const unsigned short* a1hb = &A1h[0][0] + arow_ * 168 + kg_;
    const unsigned short* a1lb = &A1l[0][0] + arow_ * 168 + kg_;
    const unsigned short* a2hb = &A2h[0][0] + arow_ * 264 + kg_;
    const unsigned short* a2lb = &A2l[0][0] + arow_ * 264 + kg_;

    { // net1 layer1 -> hidden (A2)
      DECL_ACC;
      GEMM_KLOOP(5, 168, a1hb, a1lb, ws + OFF_W1H + wbase_, ws + OFF_W1L + wbase_);
      STORE_H_ALL(sbias[0]);
    }
    __syncthreads();
    { // net1 layer2 -> q1 partials
      DECL_ACC;
      GEMM_KLOOP(8, 264, a2hb, a2lb, ws + OFF_W2H + wbase_, ws + OFF_W2L + wbase_);
      ACCQ_ALL(sbias[1], swr[0], qp1_0, qp1_1, qp1_2, qp1_3);
    }
    __syncthreads();
    { // net2 layer1 -> hidden (A2)
      DECL_ACC;
      GEMM_KLOOP(5, 168, a1hb, a1lb, ws + OFF_W3H + wbase_, ws + OFF_W3L + wbase_);
      STORE_H_ALL(sbias[2]);
    }
    __syncthreads();
    { // net2 layer2 -> q2 partials
      DECL_ACC;
      GEMM_KLOOP(8, 264, a2hb, a2lb, ws + OFF_W4H + wbase_, ws + OFF_W4L + wbase_);
      ACCQ_ALL(sbias[3], swr[1], qp2_0, qp2_1, qp2_2, qp2_3);
    }
    __syncthreads();  // A2 fully consumed before next object's build/L1 reuse
  }

  // ---- readout: reduce q partials over the 16 col-lanes, then waves -------
  QREDUCE(qp1_0, qp2_0, 0)
  QREDUCE(qp1_1, qp2_1, 1)
  QREDUCE(qp1_2, qp2_2, 2)
  QREDUCE(qp1_3, qp2_3, 3)
  __syncthreads();
  if (tid < 128) {
    int net = tid >> 6, r = tid & 63;
    float s = 0.f;
#pragma unroll
    for (int w = 0; w < 8; ++w) s += qbuf[net][w][r];
    s += net ? br2[0] : br1[0];
    __builtin_nontemporal_store(s, out + net * B_TOT + b0 + r);
  }
}

// ---------------------------------------------------------------------------
extern "C" void kernel_launch(void* const* d_in, const int* in_sizes, int n_in,
                              void* d_out, int out_size, void* d_ws, size_t ws_size,
                              hipStream_t stream) {
  (void)in_sizes; (void)n_in; (void)out_size; (void)ws_size;
  const float* obs = (const float*)d_in[0];
  // d_in[1] (act) is unused by the reference.
  const float* ef  = (const float*)d_in[2];
  const int*   eto = (const int*)d_in[3];
  const float* w1  = (const float*)d_in[4];  const float* b1  = (const float*)d_in[5];
  const float* w2  = (const float*)d_in[6];  const float* b2  = (const float*)d_in[7];
  const float* w3  = (const float*)d_in[8];  const float* b3  = (const float*)d_in[9];
  const float* w4  = (const float*)d_in[10]; const float* b4  = (const float*)d_in[11];
  const float* wr1 = (const float*)d_in[12]; const float* br1 = (const float*)d_in[13];
  const float* wr2 = (const float*)d_in[14]; const float* br2 = (const float*)d_in[15];
  float* out = (float*)d_out;
  unsigned short* ws = (unsigned short*)d_ws;  // needs 832 KB

  prep_weights<<<416, 64, 0, stream>>>(w1, w2, w3, w4, ws);
  gnn_fused<<<B_TOT / MB, 512, 0, stream>>>(obs, ef, eto, ws,
                                            b1, b2, b3, b4, wr1, br1, wr2, br2, out);
}

// Round 6
// 847.172 us; speedup vs baseline: 2.2609x; 1.0072x over previous
//
#include <hip/hip_runtime.h>
#include <hip/hip_bf16.h>
#include <stdint.h>

// ---------------------------------------------------------------------------
// GnnCritic fused forward, MI355X (gfx950) — v4.
//
// q{1,2}[b] = sum_n relu(relu(inp[n,b] @ W1 + b1) @ W2 + b2) @ wr + br
// inp[n,b]  = [obs_body(10) | obs_obj_n(15) | segmax_n(edge_features)(128)]
//
// v4 vs v3: ONE change — __launch_bounds__(512, 2) -> (512, 1).
// Rationale: v1/v2/v3 all report VGPR_Count == exactly 128 (clamp value) with
// ~820 MB of symmetric excess FETCH+WRITE = in-loop spill-fill scratch
// traffic. Pressure arithmetic wants ~160-180 VGPRs (acc 32 + >=1.5 kf-rounds
// of fragments in flight 72 + addressing). LDS (118 KB) already caps us at
// 1 block/CU = 2 waves/SIMD, so the 4-waves/EU occupancy the 128-clamp
// preserves is unreachable — the clamp only buys spills. (512,1) raises the
// allocator budget to 512 VGPRs/wave.
// ---------------------------------------------------------------------------

#define B_TOT 65536
#define MB 64

typedef __bf16 bf16x8 __attribute__((ext_vector_type(8)));
typedef float f32x4 __attribute__((ext_vector_type(4)));
typedef unsigned short u16x8 __attribute__((ext_vector_type(8)));

// packed-weight offsets in d_ws, in ushort units (frag = 64 lanes x 8 bf16)
#define OFF_W1H 0        // 80 frags  (K=160: kf 0..4, 16 cfg)
#define OFF_W1L 40960
#define OFF_W2H 81920    // 128 frags (K=256: kf 0..7)
#define OFF_W2L 147456
#define OFF_W3H 212992
#define OFF_W3L 253952
#define OFF_W4H 294912
#define OFF_W4L 360448   // end = 425984 ushorts = 832 KB

__device__ __forceinline__ unsigned short f2bf(float f) {  // RNE
  unsigned int u = __float_as_uint(f);
  u += 0x7fffu + ((u >> 16) & 1u);
  return (unsigned short)(u >> 16);
}
__device__ __forceinline__ float bf2f(unsigned short h) {
  return __uint_as_float(((unsigned int)h) << 16);
}
__device__ __forceinline__ void split2(float v, unsigned short& h, unsigned short& l) {
  h = f2bf(v);
  l = f2bf(v - bf2f(h));
}

// ---------------------------------------------------------------------------
// Prep: pack W (Kreal x 256 row-major fp32) into B-fragment order, hi/lo bf16.
// Fragment (kf,cfg): lane L, elem j holds W[kf*32 + (L>>4)*8 + j][cfg*16 + (L&15)].
// ---------------------------------------------------------------------------
__global__ void prep_weights(const float* __restrict__ w1, const float* __restrict__ w2,
                             const float* __restrict__ w3, const float* __restrict__ w4,
                             unsigned short* __restrict__ ws) {
  int bid = blockIdx.x;
  int lane = threadIdx.x;
  const float* w; int f, Kreal; unsigned short *oh, *ol;
  if (bid < 80)       { w = w1; f = bid;       Kreal = 153; oh = ws + OFF_W1H; ol = ws + OFF_W1L; }
  else if (bid < 208) { w = w2; f = bid - 80;  Kreal = 256; oh = ws + OFF_W2H; ol = ws + OFF_W2L; }
  else if (bid < 288) { w = w3; f = bid - 208; Kreal = 153; oh = ws + OFF_W3H; ol = ws + OFF_W3L; }
  else                { w = w4; f = bid - 288; Kreal = 256; oh = ws + OFF_W4H; ol = ws + OFF_W4L; }
  int kf = f >> 4, cfg = f & 15;
  int c  = cfg * 16 + (lane & 15);
  int kb = kf * 32 + (lane >> 4) * 8;
  u16x8 H, L;
#pragma unroll
  for (int j = 0; j < 8; ++j) {
    int k = kb + j;
    float v = (k < Kreal) ? w[k * 256 + c] : 0.f;
    unsigned short h, l; split2(v, h, l);
    H[j] = h; L[j] = l;
  }
  size_t idx = ((size_t)f * 64 + lane) * 8;
  *(u16x8*)(oh + idx) = H;
  *(u16x8*)(ol + idx) = L;
}

// ---------------------------------------------------------------------------
// GEMM-phase macros. All state is NAMED locals; everything static after the
// (fully unrolled) kf loop. Wave owns output cols wave*32..+32 (cfg wave*2+cf).
// acc cRF_CF: D rows rf*16 + (lane>>4)*4 + i, col = wave*32 + cf*16 + (lane&15).
// ---------------------------------------------------------------------------
#define Z4 ((f32x4){0.f, 0.f, 0.f, 0.f})

#define DECL_ACC \
  f32x4 c00 = Z4, c01 = Z4, c10 = Z4, c11 = Z4, c20 = Z4, c21 = Z4, c30 = Z4, c31 = Z4

#define MFMA3(CC, AH, AL, BH, BL)                                              \
  do {                                                                         \
    CC = __builtin_amdgcn_mfma_f32_16x16x32_bf16(AH, BH, CC, 0, 0, 0);         \
    CC = __builtin_amdgcn_mfma_f32_16x16x32_bf16(AL, BH, CC, 0, 0, 0);         \
    CC = __builtin_amdgcn_mfma_f32_16x16x32_bf16(AH, BL, CC, 0, 0, 0);         \
  } while (0)

// KF: #kf-rounds; AS: A-tile row stride (ushorts). AHB/ALB: per-thread A base
// (row lane&15, +((lane>>4)*8)). WHB/WLB: per-thread W base (+wave*1024+lane*8).
#define GEMM_KLOOP(KF, AS, AHB, ALB, WHB, WLB)                                 \
  _Pragma("unroll")                                                            \
  for (int kf = 0; kf < (KF); ++kf) {                                          \
    const unsigned short* ah_ = (AHB) + kf * 32;                               \
    const unsigned short* al_ = (ALB) + kf * 32;                               \
    bf16x8 a0h = *(const bf16x8*)(ah_ + 0 * 16 * (AS));                        \
    bf16x8 a1h = *(const bf16x8*)(ah_ + 1 * 16 * (AS));                        \
    bf16x8 a2h = *(const bf16x8*)(ah_ + 2 * 16 * (AS));                        \
    bf16x8 a3h = *(const bf16x8*)(ah_ + 3 * 16 * (AS));                        \
    bf16x8 a0l = *(const bf16x8*)(al_ + 0 * 16 * (AS));                        \
    bf16x8 a1l = *(const bf16x8*)(al_ + 1 * 16 * (AS));                        \
    bf16x8 a2l = *(const bf16x8*)(al_ + 2 * 16 * (AS));                        \
    bf16x8 a3l = *(const bf16x8*)(al_ + 3 * 16 * (AS));                        \
    const unsigned short* wh_ = (WHB) + (size_t)kf * 8192;                     \
    const unsigned short* wl_ = (WLB) + (size_t)kf * 8192;                     \
    bf16x8 b0h = *(const bf16x8*)(wh_);                                        \
    bf16x8 b0l = *(const bf16x8*)(wl_);                                        \
    bf16x8 b1h = *(const bf16x8*)(wh_ + 512);                                  \
    bf16x8 b1l = *(const bf16x8*)(wl_ + 512);                                  \
    MFMA3(c00, a0h, a0l, b0h, b0l);                                            \
    MFMA3(c10, a1h, a1l, b0h, b0l);                                            \
    MFMA3(c20, a2h, a2l, b0h, b0l);                                            \
    MFMA3(c30, a3h, a3l, b0h, b0l);                                            \
    MFMA3(c01, a0h, a0l, b1h, b1l);                                            \
    MFMA3(c11, a1h, a1l, b1h, b1l);                                            \
    MFMA3(c21, a2h, a2l, b1h, b1l);                                            \
    MFMA3(c31, a3h, a3l, b1h, b1l);                                            \
  }

// relu(acc+bias) -> split hi/lo -> A2 LDS tile (ushort scatter).
#define STORE_H_ONE(CC, RF, CF, BIASROW)                                       \
  do {                                                                         \
    int col = col0_ + (CF) * 16;                                               \
    float bv = (BIASROW)[col];                                                 \
    _Pragma("unroll")                                                          \
    for (int i = 0; i < 4; ++i) {                                              \
      int row = (RF) * 16 + row0_ + i;                                         \
      float h = fmaxf(CC[i] + bv, 0.f);                                        \
      unsigned short hh, hl; split2(h, hh, hl);                                \
      A2h[row][col] = hh; A2l[row][col] = hl;                                  \
    }                                                                          \
  } while (0)

#define STORE_H_ALL(BIASROW)                                                   \
  do {                                                                         \
    STORE_H_ONE(c00, 0, 0, BIASROW); STORE_H_ONE(c01, 0, 1, BIASROW);          \
    STORE_H_ONE(c10, 1, 0, BIASROW); STORE_H_ONE(c11, 1, 1, BIASROW);          \
    STORE_H_ONE(c20, 2, 0, BIASROW); STORE_H_ONE(c21, 2, 1, BIASROW);          \
    STORE_H_ONE(c30, 3, 0, BIASROW); STORE_H_ONE(c31, 3, 1, BIASROW);          \
  } while (0)

// relu(acc+bias)*wr accumulated into per-row q partial vector QPV (f32x4).
#define ACCQ_ONE(CC, CF, BIASROW, WRROW, QPV)                                  \
  do {                                                                         \
    int col = col0_ + (CF) * 16;                                               \
    float bv = (BIASROW)[col];                                                 \
    float wv = (WRROW)[col];                                                   \
    _Pragma("unroll")                                                          \
    for (int i = 0; i < 4; ++i) {                                              \
      float x = fmaxf(CC[i] + bv, 0.f);                                        \
      QPV[i] += x * wv;                                                        \
    }                                                                          \
  } while (0)

#define ACCQ_ALL(BIASROW, WRROW, Q0, Q1, Q2, Q3)                               \
  do {                                                                         \
    ACCQ_ONE(c00, 0, BIASROW, WRROW, Q0); ACCQ_ONE(c01, 1, BIASROW, WRROW, Q0);\
    ACCQ_ONE(c10, 0, BIASROW, WRROW, Q1); ACCQ_ONE(c11, 1, BIASROW, WRROW, Q1);\
    ACCQ_ONE(c20, 0, BIASROW, WRROW, Q2); ACCQ_ONE(c21, 1, BIASROW, WRROW, Q2);\
    ACCQ_ONE(c30, 0, BIASROW, WRROW, Q3); ACCQ_ONE(c31, 1, BIASROW, WRROW, Q3);\
  } while (0)

#define QREDUCE(QPV1, QPV2, RF)                                                \
  _Pragma("unroll")                                                            \
  for (int i = 0; i < 4; ++i) {                                                \
    float v1 = QPV1[i], v2 = QPV2[i];                                          \
    _Pragma("unroll")                                                          \
    for (int m = 1; m < 16; m <<= 1) {                                         \
      v1 += __shfl_xor(v1, m);                                                 \
      v2 += __shfl_xor(v2, m);                                                 \
    }                                                                          \
    if ((lane & 15) == 0) {                                                    \
      int row = (RF) * 16 + row0_ + i;                                         \
      qbuf[0][wave][row] = v1;                                                 \
      qbuf[1][wave][row] = v2;                                                 \
    }                                                                          \
  }

// ---------------------------------------------------------------------------
// Main kernel: 512 threads (8 waves, 1x8 row x col split), 64 batch rows per
// block, grid = 1024. LDS ~116 KB -> 1 block/CU (8 waves = 2/SIMD).
// ---------------------------------------------------------------------------
__global__ __launch_bounds__(512, 1) void gnn_fused(
    const float* __restrict__ obs, const float* __restrict__ ef, const int* __restrict__ eto,
    const unsigned short* __restrict__ ws,
    const float* __restrict__ b1, const float* __restrict__ b2,
    const float* __restrict__ b3, const float* __restrict__ b4,
    const float* __restrict__ wr1, const float* __restrict__ br1,
    const float* __restrict__ wr2, const float* __restrict__ br2,
    float* __restrict__ out) {
  // row strides 168/264 ushorts: 16B-aligned rows (ds_read_b128), stride mod
  // 32 dwords has gcd 4 -> 2-way read aliasing (free per m136).
  __shared__ __attribute__((aligned(16))) unsigned short A1h[64][168];
  __shared__ __attribute__((aligned(16))) unsigned short A1l[64][168];
  __shared__ __attribute__((aligned(16))) unsigned short A2h[64][264];
  __shared__ __attribute__((aligned(16))) unsigned short A2l[64][264];
  __shared__ float sbias[4][256];
  __shared__ float swr[2][256];
  __shared__ float qbuf[2][8][64];

  const int tid  = threadIdx.x;
  const int lane = tid & 63;
  const int wave = tid >> 6;
  const int b0   = blockIdx.x * MB;

  const int arow_ = lane & 15;          // A-frag row within 16-row group
  const int kg_   = (lane >> 4) * 8;    // k-slice within frag
  const int row0_ = (lane >> 4) << 2;   // C-frag row base
  const int col0_ = wave * 32 + arow_;  // C-frag col base
  const size_t wbase_ = (size_t)wave * 1024 + (size_t)lane * 8;

  if (tid < 256) {
    sbias[0][tid] = b1[tid]; sbias[1][tid] = b2[tid];
    sbias[2][tid] = b3[tid]; sbias[3][tid] = b4[tid];
    swr[0][tid]   = wr1[tid]; swr[1][tid]  = wr2[tid];
  }
  const int e0 = eto[0], e1 = eto[1], e2 = eto[2];
  const int e3 = eto[3], e4 = eto[4], e5 = eto[5];

  f32x4 qp1_0 = Z4, qp1_1 = Z4, qp1_2 = Z4, qp1_3 = Z4;
  f32x4 qp2_0 = Z4, qp2_1 = Z4, qp2_2 = Z4, qp2_3 = Z4;

  for (int n = 0; n < 3; ++n) {
    // ---- build A1 = [body | obj_n | segmax_n(ef)] as hi/lo bf16 ----------
    for (int idx = tid; idx < 64 * 32; idx += 512) {   // cols 0..24
      int r = idx >> 5, k = idx & 31;
      if (k < 25) {
        int b = b0 + r;
        float v = (k < 10) ? obs[b * 55 + k] : obs[b * 55 + 10 + n * 15 + (k - 10)];
        unsigned short h, l; split2(v, h, l);
        A1h[r][k] = h; A1l[r][k] = l;
      }
    }
    for (int idx = tid; idx < 64 * 16; idx += 512) {   // zero pad 153..167
      int r = idx >> 4, k = 153 + (idx & 15);
      if (k < 168) { A1h[r][k] = 0; A1l[r][k] = 0; }
    }
#pragma unroll
    for (int it = 0; it < 4; ++it) {                   // segmax, cols 25..152
      int job = tid + it * 512;                        // 64 rows x 32 float4
      int r = job >> 5, dq = job & 31;
      const float* efb = ef + ((size_t)(b0 + r) * 6) * 128 + dq * 4;
      float m0 = -3.0e38f, m1 = m0, m2 = m0, m3 = m0;
      // nt loads: ef is stream-once; keep packed weights L2-resident.
#define SEGMAX_EDGE(E, TGT)                                                    \
      if ((TGT) == n) {                                                        \
        f32x4 v = __builtin_nontemporal_load((const f32x4*)(efb + (E) * 128)); \
        m0 = fmaxf(m0, v[0]); m1 = fmaxf(m1, v[1]);                            \
        m2 = fmaxf(m2, v[2]); m3 = fmaxf(m3, v[3]);                            \
      }
      SEGMAX_EDGE(0, e0) SEGMAX_EDGE(1, e1) SEGMAX_EDGE(2, e2)
      SEGMAX_EDGE(3, e3) SEGMAX_EDGE(4, e4) SEGMAX_EDGE(5, e5)
#undef SEGMAX_EDGE
      int c = 25 + dq * 4;
      unsigned short h, l;
      split2(m0, h, l); A1h[r][c + 0] = h; A1l[r][c + 0] = l;
      split2(m1, h, l); A1h[r][c + 1] = h; A1l[r][c + 1] = l;
      split2(m2, h, l); A1h[r][c + 2] = h; A1l[r][c + 2] = l;
      split2(m3, h, l); A1h[r][c + 3] = h; A1l[r][c + 3] = l;
    }
    __syncthreads();

    const unsigned short* a1hb = &A1h[0][0] + arow_ * 168 + kg_;
    const unsigned short* a1lb = &A1l[0][0] + arow_ * 168 + kg_;
    const unsigned short* a2hb = &A2h[0][0] + arow_ * 264 + kg_;
    const unsigned short* a2lb = &A2l[0][0] + arow_ * 264 + kg_;

    { // net1 layer1 -> hidden (A2)
      DECL_ACC;
      GEMM_KLOOP(5, 168, a1hb, a1lb, ws + OFF_W1H + wbase_, ws + OFF_W1L + wbase_);
      STORE_H_ALL(sbias[0]);
    }
    __syncthreads();
    { // net1 layer2 -> q1 partials
      DECL_ACC;
      GEMM_KLOOP(8, 264, a2hb, a2lb, ws + OFF_W2H + wbase_, ws + OFF_W2L + wbase_);
      ACCQ_ALL(sbias[1], swr[0], qp1_0, qp1_1, qp1_2, qp1_3);
    }
    __syncthreads();
    { // net2 layer1 -> hidden (A2)
      DECL_ACC;
      GEMM_KLOOP(5, 168, a1hb, a1lb, ws + OFF_W3H + wbase_, ws + OFF_W3L + wbase_);
      STORE_H_ALL(sbias[2]);
    }
    __syncthreads();
    { // net2 layer2 -> q2 partials
      DECL_ACC;
      GEMM_KLOOP(8, 264, a2hb, a2lb, ws + OFF_W4H + wbase_, ws + OFF_W4L + wbase_);
      ACCQ_ALL(sbias[3], swr[1], qp2_0, qp2_1, qp2_2, qp2_3);
    }
    __syncthreads();  // A2 fully consumed before next object's build/L1 reuse
  }

  // ---- readout: reduce q partials over the 16 col-lanes, then waves -------
  QREDUCE(qp1_0, qp2_0, 0)
  QREDUCE(qp1_1, qp2_1, 1)
  QREDUCE(qp1_2, qp2_2, 2)
  QREDUCE(qp1_3, qp2_3, 3)
  __syncthreads();
  if (tid < 128) {
    int net = tid >> 6, r = tid & 63;
    float s = 0.f;
#pragma unroll
    for (int w = 0; w < 8; ++w) s += qbuf[net][w][r];
    s += net ? br2[0] : br1[0];
    __builtin_nontemporal_store(s, out + net * B_TOT + b0 + r);
  }
}

// ---------------------------------------------------------------------------
extern "C" void kernel_launch(void* const* d_in, const int* in_sizes, int n_in,
                              void* d_out, int out_size, void* d_ws, size_t ws_size,
                              hipStream_t stream) {
  (void)in_sizes; (void)n_in; (void)out_size; (void)ws_size;
  const float* obs = (const float*)d_in[0];
  // d_in[1] (act) is unused by the reference.
  const float* ef  = (const float*)d_in[2];
  const int*   eto = (const int*)d_in[3];
  const float* w1  = (const float*)d_in[4];  const float* b1  = (const float*)d_in[5];
  const float* w2  = (const float*)d_in[6];  const float* b2  = (const float*)d_in[7];
  const float* w3  = (const float*)d_in[8];  const float* b3  = (const float*)d_in[9];
  const float* w4  = (const float*)d_in[10]; const float* b4  = (const float*)d_in[11];
  const float* wr1 = (const float*)d_in[12]; const float* br1 = (const float*)d_in[13];
  const float* wr2 = (const float*)d_in[14]; const float* br2 = (const float*)d_in[15];
  float* out = (float*)d_out;
  unsigned short* ws = (unsigned short*)d_ws;  // needs 832 KB

  prep_weights<<<416, 64, 0, stream>>>(w1, w2, w3, w4, ws);
  gnn_fused<<<B_TOT / MB, 512, 0, stream>>>(obs, ef, eto, ws,
                                            b1, b2, b3, b4, wr1, br1, wr2, br2, out);
}

// Round 7
// 843.423 us; speedup vs baseline: 2.2709x; 1.0044x over previous
//
#include <hip/hip_runtime.h>
#include <hip/hip_bf16.h>
#include <stdint.h>

// ---------------------------------------------------------------------------
// GnnCritic fused forward, MI355X (gfx950) — v5.
//
// q{1,2}[b] = sum_n relu(relu(inp[n,b] @ W1 + b1) @ W2 + b2) @ wr + br
// inp[n,b]  = [obs_body(10) | obs_obj_n(15) | segmax_n(edge_features)(128)]
//
// v5 vs v3/v4: eliminate the 32 always-live q-partial VGPRs (the spill
// trigger: 32 acc + 32 qp + 48 frags + ~15 addr > 128 cap). Q-partials now
// accumulate into LDS qbuf per ACCQ phase via a 16-lane shfl reduce. In-loop
// live set drops to ~95 VGPRs. launch_bounds back to (512,2) ((512,1) was a
// no-op for allocation and -15% on scheduling).
// ---------------------------------------------------------------------------

#define B_TOT 65536
#define MB 64

typedef __bf16 bf16x8 __attribute__((ext_vector_type(8)));
typedef float f32x4 __attribute__((ext_vector_type(4)));
typedef unsigned short u16x8 __attribute__((ext_vector_type(8)));

// packed-weight offsets in d_ws, in ushort units (frag = 64 lanes x 8 bf16)
#define OFF_W1H 0        // 80 frags  (K=160: kf 0..4, 16 cfg)
#define OFF_W1L 40960
#define OFF_W2H 81920    // 128 frags (K=256: kf 0..7)
#define OFF_W2L 147456
#define OFF_W3H 212992
#define OFF_W3L 253952
#define OFF_W4H 294912
#define OFF_W4L 360448   // end = 425984 ushorts = 832 KB

__device__ __forceinline__ unsigned short f2bf(float f) {  // RNE
  unsigned int u = __float_as_uint(f);
  u += 0x7fffu + ((u >> 16) & 1u);
  return (unsigned short)(u >> 16);
}
__device__ __forceinline__ float bf2f(unsigned short h) {
  return __uint_as_float(((unsigned int)h) << 16);
}
__device__ __forceinline__ void split2(float v, unsigned short& h, unsigned short& l) {
  h = f2bf(v);
  l = f2bf(v - bf2f(h));
}

// ---------------------------------------------------------------------------
// Prep: pack W (Kreal x 256 row-major fp32) into B-fragment order, hi/lo bf16.
// Fragment (kf,cfg): lane L, elem j holds W[kf*32 + (L>>4)*8 + j][cfg*16 + (L&15)].
// ---------------------------------------------------------------------------
__global__ void prep_weights(const float* __restrict__ w1, const float* __restrict__ w2,
                             const float* __restrict__ w3, const float* __restrict__ w4,
                             unsigned short* __restrict__ ws) {
  int bid = blockIdx.x;
  int lane = threadIdx.x;
  const float* w; int f, Kreal; unsigned short *oh, *ol;
  if (bid < 80)       { w = w1; f = bid;       Kreal = 153; oh = ws + OFF_W1H; ol = ws + OFF_W1L; }
  else if (bid < 208) { w = w2; f = bid - 80;  Kreal = 256; oh = ws + OFF_W2H; ol = ws + OFF_W2L; }
  else if (bid < 288) { w = w3; f = bid - 208; Kreal = 153; oh = ws + OFF_W3H; ol = ws + OFF_W3L; }
  else                { w = w4; f = bid - 288; Kreal = 256; oh = ws + OFF_W4H; ol = ws + OFF_W4L; }
  int kf = f >> 4, cfg = f & 15;
  int c  = cfg * 16 + (lane & 15);
  int kb = kf * 32 + (lane >> 4) * 8;
  u16x8 H, L;
#pragma unroll
  for (int j = 0; j < 8; ++j) {
    int k = kb + j;
    float v = (k < Kreal) ? w[k * 256 + c] : 0.f;
    unsigned short h, l; split2(v, h, l);
    H[j] = h; L[j] = l;
  }
  size_t idx = ((size_t)f * 64 + lane) * 8;
  *(u16x8*)(oh + idx) = H;
  *(u16x8*)(ol + idx) = L;
}

// ---------------------------------------------------------------------------
// GEMM-phase macros. All state is NAMED locals. Wave owns output cols
// wave*32..+32 (cfg wave*2+cf). acc cRF_CF: D rows rf*16 + (lane>>4)*4 + i,
// col = wave*32 + cf*16 + (lane&15).
// ---------------------------------------------------------------------------
#define Z4 ((f32x4){0.f, 0.f, 0.f, 0.f})

#define DECL_ACC \
  f32x4 c00 = Z4, c01 = Z4, c10 = Z4, c11 = Z4, c20 = Z4, c21 = Z4, c30 = Z4, c31 = Z4

#define MFMA3(CC, AH, AL, BH, BL)                                              \
  do {                                                                         \
    CC = __builtin_amdgcn_mfma_f32_16x16x32_bf16(AH, BH, CC, 0, 0, 0);         \
    CC = __builtin_amdgcn_mfma_f32_16x16x32_bf16(AL, BH, CC, 0, 0, 0);         \
    CC = __builtin_amdgcn_mfma_f32_16x16x32_bf16(AH, BL, CC, 0, 0, 0);         \
  } while (0)

// KF: #kf-rounds; AS: A-tile row stride (ushorts). AHB/ALB: per-thread A base
// (row lane&15, +((lane>>4)*8)). WHB/WLB: per-thread W base (+wave*1024+lane*8).
#define GEMM_KLOOP(KF, AS, AHB, ALB, WHB, WLB)                                 \
  _Pragma("unroll")                                                            \
  for (int kf = 0; kf < (KF); ++kf) {                                          \
    const unsigned short* ah_ = (AHB) + kf * 32;                               \
    const unsigned short* al_ = (ALB) + kf * 32;                               \
    bf16x8 a0h = *(const bf16x8*)(ah_ + 0 * 16 * (AS));                        \
    bf16x8 a1h = *(const bf16x8*)(ah_ + 1 * 16 * (AS));                        \
    bf16x8 a2h = *(const bf16x8*)(ah_ + 2 * 16 * (AS));                        \
    bf16x8 a3h = *(const bf16x8*)(ah_ + 3 * 16 * (AS));                        \
    bf16x8 a0l = *(const bf16x8*)(al_ + 0 * 16 * (AS));                        \
    bf16x8 a1l = *(const bf16x8*)(al_ + 1 * 16 * (AS));                        \
    bf16x8 a2l = *(const bf16x8*)(al_ + 2 * 16 * (AS));                        \
    bf16x8 a3l = *(const bf16x8*)(al_ + 3 * 16 * (AS));                        \
    const unsigned short* wh_ = (WHB) + (size_t)kf * 8192;                     \
    const unsigned short* wl_ = (WLB) + (size_t)kf * 8192;                     \
    bf16x8 b0h = *(const bf16x8*)(wh_);                                        \
    bf16x8 b0l = *(const bf16x8*)(wl_);                                        \
    bf16x8 b1h = *(const bf16x8*)(wh_ + 512);                                  \
    bf16x8 b1l = *(const bf16x8*)(wl_ + 512);                                  \
    MFMA3(c00, a0h, a0l, b0h, b0l);                                            \
    MFMA3(c10, a1h, a1l, b0h, b0l);                                            \
    MFMA3(c20, a2h, a2l, b0h, b0l);                                            \
    MFMA3(c30, a3h, a3l, b0h, b0l);                                            \
    MFMA3(c01, a0h, a0l, b1h, b1l);                                            \
    MFMA3(c11, a1h, a1l, b1h, b1l);                                            \
    MFMA3(c21, a2h, a2l, b1h, b1l);                                            \
    MFMA3(c31, a3h, a3l, b1h, b1l);                                            \
  }

// relu(acc+bias) -> split hi/lo -> A2 LDS tile (ushort scatter).
#define STORE_H_ONE(CC, RF, CF, BIASROW)                                       \
  do {                                                                         \
    int col = col0_ + (CF) * 16;                                               \
    float bv = (BIASROW)[col];                                                 \
    _Pragma("unroll")                                                          \
    for (int i = 0; i < 4; ++i) {                                              \
      int row = (RF) * 16 + row0_ + i;                                         \
      float h = fmaxf(CC[i] + bv, 0.f);                                        \
      unsigned short hh, hl; split2(h, hh, hl);                                \
      A2h[row][col] = hh; A2l[row][col] = hl;                                  \
    }                                                                          \
  } while (0)

#define STORE_H_ALL(BIASROW)                                                   \
  do {                                                                         \
    STORE_H_ONE(c00, 0, 0, BIASROW); STORE_H_ONE(c01, 0, 1, BIASROW);          \
    STORE_H_ONE(c10, 1, 0, BIASROW); STORE_H_ONE(c11, 1, 1, BIASROW);          \
    STORE_H_ONE(c20, 2, 0, BIASROW); STORE_H_ONE(c21, 2, 1, BIASROW);          \
    STORE_H_ONE(c30, 3, 0, BIASROW); STORE_H_ONE(c31, 3, 1, BIASROW);          \
  } while (0)

// Per-phase q accumulation: relu(acc+bias)*wr, fold cf0+cf1, 16-lane shfl
// reduce, one lane adds into the wave-private qbuf slice. No persistent
// q registers (this removes the 32 always-live VGPRs that forced spills).
#define ACCQ_PAIR(CA, CB, RF, NET)                                             \
  _Pragma("unroll")                                                            \
  for (int i = 0; i < 4; ++i) {                                                \
    float v = fmaxf(CA[i] + bva_, 0.f) * wva_ + fmaxf(CB[i] + bvb_, 0.f) * wvb_;\
    v += __shfl_xor(v, 1); v += __shfl_xor(v, 2);                              \
    v += __shfl_xor(v, 4); v += __shfl_xor(v, 8);                              \
    if ((lane & 15) == 0) qbuf[NET][wave][(RF) * 16 + row0_ + i] += v;         \
  }

#define ACCQ_RED(NET, BIASROW, WRROW)                                          \
  do {                                                                         \
    float bva_ = (BIASROW)[col0_];      float wva_ = (WRROW)[col0_];           \
    float bvb_ = (BIASROW)[col0_ + 16]; float wvb_ = (WRROW)[col0_ + 16];      \
    ACCQ_PAIR(c00, c01, 0, NET);                                               \
    ACCQ_PAIR(c10, c11, 1, NET);                                               \
    ACCQ_PAIR(c20, c21, 2, NET);                                               \
    ACCQ_PAIR(c30, c31, 3, NET);                                               \
  } while (0)

// ---------------------------------------------------------------------------
// Main kernel: 512 threads (8 waves, 1x8 row x col split), 64 batch rows per
// block, grid = 1024. LDS ~116 KB -> 1 block/CU (8 waves = 2/SIMD).
// ---------------------------------------------------------------------------
__global__ __launch_bounds__(512, 2) void gnn_fused(
    const float* __restrict__ obs, const float* __restrict__ ef, const int* __restrict__ eto,
    const unsigned short* __restrict__ ws,
    const float* __restrict__ b1, const float* __restrict__ b2,
    const float* __restrict__ b3, const float* __restrict__ b4,
    const float* __restrict__ wr1, const float* __restrict__ br1,
    const float* __restrict__ wr2, const float* __restrict__ br2,
    float* __restrict__ out) {
  // row strides 168/264 ushorts: 16B-aligned rows (ds_read_b128), stride mod
  // 32 dwords has gcd 4 -> 2-way read aliasing (free per m136).
  __shared__ __attribute__((aligned(16))) unsigned short A1h[64][168];
  __shared__ __attribute__((aligned(16))) unsigned short A1l[64][168];
  __shared__ __attribute__((aligned(16))) unsigned short A2h[64][264];
  __shared__ __attribute__((aligned(16))) unsigned short A2l[64][264];
  __shared__ float sbias[4][256];
  __shared__ float swr[2][256];
  __shared__ float qbuf[2][8][64];

  const int tid  = threadIdx.x;
  const int lane = tid & 63;
  const int wave = tid >> 6;
  const int b0   = blockIdx.x * MB;

  const int arow_ = lane & 15;          // A-frag row within 16-row group
  const int kg_   = (lane >> 4) * 8;    // k-slice within frag
  const int row0_ = (lane >> 4) << 2;   // C-frag row base
  const int col0_ = wave * 32 + arow_;  // C-frag col base
  const size_t wbase_ = (size_t)wave * 1024 + (size_t)lane * 8;

  if (tid < 256) {
    sbias[0][tid] = b1[tid]; sbias[1][tid] = b2[tid];
    sbias[2][tid] = b3[tid]; sbias[3][tid] = b4[tid];
    swr[0][tid]   = wr1[tid]; swr[1][tid]  = wr2[tid];
  }
  // zero the q accumulation buffer (1024 floats)
  ((float*)qbuf)[tid] = 0.f;
  ((float*)qbuf)[tid + 512] = 0.f;

  const int e0 = eto[0], e1 = eto[1], e2 = eto[2];
  const int e3 = eto[3], e4 = eto[4], e5 = eto[5];

  for (int n = 0; n < 3; ++n) {
    // ---- build A1 = [body | obj_n | segmax_n(ef)] as hi/lo bf16 ----------
    for (int idx = tid; idx < 64 * 32; idx += 512) {   // cols 0..24
      int r = idx >> 5, k = idx & 31;
      if (k < 25) {
        int b = b0 + r;
        float v = (k < 10) ? obs[b * 55 + k] : obs[b * 55 + 10 + n * 15 + (k - 10)];
        unsigned short h, l; split2(v, h, l);
        A1h[r][k] = h; A1l[r][k] = l;
      }
    }
    for (int idx = tid; idx < 64 * 16; idx += 512) {   // zero pad 153..167
      int r = idx >> 4, k = 153 + (idx & 15);
      if (k < 168) { A1h[r][k] = 0; A1l[r][k] = 0; }
    }
#pragma unroll
    for (int it = 0; it < 4; ++it) {                   // segmax, cols 25..152
      int job = tid + it * 512;                        // 64 rows x 32 float4
      int r = job >> 5, dq = job & 31;
      const float* efb = ef + ((size_t)(b0 + r) * 6) * 128 + dq * 4;
      float m0 = -3.0e38f, m1 = m0, m2 = m0, m3 = m0;
      // nt loads: ef is stream-once; keep packed weights L2-resident.
#define SEGMAX_EDGE(E, TGT)                                                    \
      if ((TGT) == n) {                                                        \
        f32x4 v = __builtin_nontemporal_load((const f32x4*)(efb + (E) * 128)); \
        m0 = fmaxf(m0, v[0]); m1 = fmaxf(m1, v[1]);                            \
        m2 = fmaxf(m2, v[2]); m3 = fmaxf(m3, v[3]);                            \
      }
      SEGMAX_EDGE(0, e0) SEGMAX_EDGE(1, e1) SEGMAX_EDGE(2, e2)
      SEGMAX_EDGE(3, e3) SEGMAX_EDGE(4, e4) SEGMAX_EDGE(5, e5)
#undef SEGMAX_EDGE
      int c = 25 + dq * 4;
      unsigned short h, l;
      split2(m0, h, l); A1h[r][c + 0] = h; A1l[r][c + 0] = l;
      split2(m1, h, l); A1h[r][c + 1] = h; A1l[r][c + 1] = l;
      split2(m2, h, l); A1h[r][c + 2] = h; A1l[r][c + 2] = l;
      split2(m3, h, l); A1h[r][c + 3] = h; A1l[r][c + 3] = l;
    }
    __syncthreads();

    const unsigned short* a1hb = &A1h[0][0] + arow_ * 168 + kg_;
    const unsigned short* a1lb = &A1l[0][0] + arow_ * 168 + kg_;
    const unsigned short* a2hb = &A2h[0][0] + arow_ * 264 + kg_;
    const unsigned short* a2lb = &A2l[0][0] + arow_ * 264 + kg_;

    { // net1 layer1 -> hidden (A2)
      DECL_ACC;
      GEMM_KLOOP(5, 168, a1hb, a1lb, ws + OFF_W1H + wbase_, ws + OFF_W1L + wbase_);
      STORE_H_ALL(sbias[0]);
    }
    __syncthreads();
    { // net1 layer2 -> q1 into qbuf[0]
      DECL_ACC;
      GEMM_KLOOP(8, 264, a2hb, a2lb, ws + OFF_W2H + wbase_, ws + OFF_W2L + wbase_);
      ACCQ_RED(0, sbias[1], swr[0]);
    }
    __syncthreads();
    { // net2 layer1 -> hidden (A2)
      DECL_ACC;
      GEMM_KLOOP(5, 168, a1hb, a1lb, ws + OFF_W3H + wbase_, ws + OFF_W3L + wbase_);
      STORE_H_ALL(sbias[2]);
    }
    __syncthreads();
    { // net2 layer2 -> q2 into qbuf[1]
      DECL_ACC;
      GEMM_KLOOP(8, 264, a2hb, a2lb, ws + OFF_W4H + wbase_, ws + OFF_W4L + wbase_);
      ACCQ_RED(1, sbias[3], swr[1]);
    }
    __syncthreads();  // A2 consumed; qbuf writes visible before next phase
  }

  // ---- readout: qbuf already holds per-wave sums over all n/cols ----------
  if (tid < 128) {
    int net = tid >> 6, r = tid & 63;
    float s = 0.f;
#pragma unroll
    for (int w = 0; w < 8; ++w) s += qbuf[net][w][r];
    s += net ? br2[0] : br1[0];
    __builtin_nontemporal_store(s, out + net * B_TOT + b0 + r);
  }
}

// ---------------------------------------------------------------------------
extern "C" void kernel_launch(void* const* d_in, const int* in_sizes, int n_in,
                              void* d_out, int out_size, void* d_ws, size_t ws_size,
                              hipStream_t stream) {
  (void)in_sizes; (void)n_in; (void)out_size; (void)ws_size;
  const float* obs = (const float*)d_in[0];
  // d_in[1] (act) is unused by the reference.
  const float* ef  = (const float*)d_in[2];
  const int*   eto = (const int*)d_in[3];
  const float* w1  = (const float*)d_in[4];  const float* b1  = (const float*)d_in[5];
  const float* w2  = (const float*)d_in[6];  const float* b2  = (const float*)d_in[7];
  const float* w3  = (const float*)d_in[8];  const float* b3  = (const float*)d_in[9];
  const float* w4  = (const float*)d_in[10]; const float* b4  = (const float*)d_in[11];
  const float* wr1 = (const float*)d_in[12]; const float* br1 = (const float*)d_in[13];
  const float* wr2 = (const float*)d_in[14]; const float* br2 = (const float*)d_in[15];
  float* out = (float*)d_out;
  unsigned short* ws = (unsigned short*)d_ws;  // needs 832 KB

  prep_weights<<<416, 64, 0, stream>>>(w1, w2, w3, w4, ws);
  gnn_fused<<<B_TOT / MB, 512, 0, stream>>>(obs, ef, eto, ws,
                                            b1, b2, b3, b4, wr1, br1, wr2, br2, out);
}